// Round 8
// baseline (57.394 us; speedup 1.0000x reference)
//
#include <hip/hip_runtime.h>

// PDF sampler (NeRF sample_pdf): one 64-lane wave per ray, search/sort-free.
// R7: persistent-ish blocks, T groups per block, double-buffered LDS staging,
// software-pipelined: compute+scatter(t) -> issue loads(t+1) -> barrier ->
// nontemporal writeback(t). Store issue becomes near-continuous and HBM read
// latency hides under writeback + next compute.
//
//  - DPP wave64 inclusive scan (row_shr 1/2/4/8 + row_bcast 15/31): pure VALU.
//  - u_j=(j+0.5)/129 uniform & sorted -> lane's cdf interval [c0,c1) owns the
//    contiguous sample range [js, js_next): O(1) estimate + 1 fixup, no search.
//  - sort(concat(exist,new)) has closed-form ranks: sample j (interval k=lane+1)
//    -> rank j+k ; exist[lane] -> rank lane+js ; exist[64]=max_bin -> rank 193
//    = the dropped element. No sort.
//  - Rows staged in LDS (scatter), block writes 8 rays = 6176 B contiguously as
//    aligned nontemporal dwordx4 (R4: fixes write amplification; R6: nt keeps
//    the 202 MB output stream from evicting L3-resident inputs).

constexpr int kNCoarse = 64;             // coarse bins per ray (== wave size)
constexpr int kNumU    = 129;            // NUM_SAMPLES + 1
constexpr int kNOut    = 193;            // output samples per ray
constexpr int kWaves   = 8;              // rays per group (= waves per block)
constexpr int kBlock   = kWaves * 64;    // 512 threads
constexpr int kGroupF  = kWaves * kNOut; // 1544 floats staged per group
constexpr int kGroupV4 = kGroupF / 4;    // 386 float4 stores per group
constexpr int kGrid    = 4096;           // blocks (chunked group assignment)

typedef float f32x4 __attribute__((ext_vector_type(4)));

// DPP update: lanes receive src per ctrl; invalid lanes keep oldv (bctrl=false) or 0 (true).
#define DPP_UPD_F(oldv, srcv, ctrl, rmask, bctrl)                             \
  __int_as_float(__builtin_amdgcn_update_dpp(                                 \
      __float_as_int(oldv), __float_as_int(srcv), (ctrl), (rmask), 0xF, (bctrl)))

__global__ __launch_bounds__(kBlock) void pdf_sampler_kernel(
    const float* __restrict__ weights,
    const float* __restrict__ bins,
    const float* __restrict__ max_bin,
    float* __restrict__ out,
    int n_rays)
{
    const int tid  = threadIdx.x;
    const int lane = tid & 63;
    const int wid  = tid >> 6;

    const int nGroups = (n_rays + kWaves - 1) / kWaves;
    const int T       = (nGroups + kGrid - 1) / kGrid;       // groups per block
    const int g0      = blockIdx.x * T;
    const int gEnd    = min(g0 + T, nGroups);
    if (g0 >= nGroups) return;

    __shared__ __align__(16) float s_m[2][kGroupF];

    // ---- prologue: issue loads for first group ----
    float w = 0.0f, b0 = 0.0f, mb = 0.0f;
    {
        const int ray = g0 * kWaves + wid;
        if (ray < n_rays) {
            w  = weights[(size_t)ray * kNCoarse + lane];
            b0 = bins[(size_t)ray * kNCoarse + lane];
            mb = max_bin[ray];
        }
    }

    int p = 0;
    for (int g = g0; g < gEnd; ++g, p ^= 1) {
        const int ray = g * kWaves + wid;

        // ---- compute + scatter into buf[p] ----
        if (ray < n_rays) {
            const float wp = w + 0.01f;                      // HIST_PAD

            // wave64 inclusive scan via DPP (6 VALU ops)
            float c = wp;
            c += DPP_UPD_F(0.0f, c, 0x111, 0xF, true);   // row_shr:1
            c += DPP_UPD_F(0.0f, c, 0x112, 0xF, true);   // row_shr:2
            c += DPP_UPD_F(0.0f, c, 0x114, 0xF, true);   // row_shr:4
            c += DPP_UPD_F(0.0f, c, 0x118, 0xF, true);   // row_shr:8
            c += DPP_UPD_F(0.0f, c, 0x142, 0xA, false);  // row_bcast:15 -> rows 1,3
            c += DPP_UPD_F(0.0f, c, 0x143, 0xC, false);  // row_bcast:31 -> rows 2,3

            const float ws        = __int_as_float(__builtin_amdgcn_readlane(__float_as_int(c), 63));
            const float padding   = fmaxf(1e-5f - ws, 0.0f);           // EPS pad
            const float inv_total = __builtin_amdgcn_rcpf(ws + padding); // ~1ulp, thr=0.098
            const float pad64     = padding * (1.0f / 64.0f);

            const float c1 = fminf((c + (float)(lane + 1) * pad64) * inv_total, 1.0f);
            const float c0 = DPP_UPD_F(0.0f, c1, 0x138, 0xF, true);   // wf_sr:1 -> cdf[lane]
            const float b1 = DPP_UPD_F(mb,   b0, 0x130, 0xF, false);  // wf_sl:1 -> exist[lane+1]

            // js = min{j : u_j >= c0}: estimate + one branchless fixup
            const float kInv = 1.0f / 129.0f, kHalf = 0.5f / 129.0f;
            int js = (int)ceilf(fmaf(c0, 129.0f, -0.5f));
            js = min(max(js, 0), kNumU);
            {
                const float um1 = fmaf((float)(js - 1), kInv, kHalf);
                const float u0e = fmaf((float)js,       kInv, kHalf);
                if (js > 0 && um1 >= c0)           js -= 1;
                else if (js < kNumU && u0e < c0)   js += 1;
            }
            const int js_next = __builtin_amdgcn_update_dpp(kNumU, js, 0x130, 0xF, 0xF, false);

            // interpolation as arithmetic sequence over this lane's samples
            const float denom  = c1 - c0;
            const float rdenom = (denom > 0.0f) ? __builtin_amdgcn_rcpf(denom) : 0.0f;
            const float dbin   = b1 - b0;
            const float u0     = fmaf((float)js, kInv, kHalf);
            const float t0     = fminf(fmaxf((u0 - c0) * rdenom, 0.0f), 1.0f);
            float       val    = fmaf(t0, dbin, b0);
            const float step   = kInv * rdenom * dbin;

            float* mrow = s_m[p] + wid * kNOut;
            mrow[lane + js] = b0;                       // exist[lane] at rank lane+js
            for (int j = js; j < js_next; ++j) {        // samples at ranks j+lane+1
                mrow[j + lane + 1] = val;
                val += step;
            }
        }

        // ---- issue next group's loads (latency hides under barrier+writeback) ----
        if (g + 1 < gEnd) {
            const int nray = (g + 1) * kWaves + wid;
            if (nray < n_rays) {
                w  = weights[(size_t)nray * kNCoarse + lane];
                b0 = bins[(size_t)nray * kNCoarse + lane];
                mb = max_bin[nray];
            } else {
                w = 0.0f; b0 = 0.0f; mb = 0.0f;
            }
        }

        __syncthreads();   // buf[p] scatter complete block-wide

        // ---- nontemporal coalesced writeback of buf[p] ----
        {
            const int raysHere = min(n_rays - g * kWaves, kWaves);
            const int nf = raysHere * kNOut;
            float* obase = out + (size_t)g * kGroupF;
            if (tid < kGroupV4) {
                const int off = tid * 4;
                if (off + 3 < nf) {
                    const f32x4 v = *reinterpret_cast<const f32x4*>(&s_m[p][off]);
                    __builtin_nontemporal_store(v, reinterpret_cast<f32x4*>(&obase[off]));
                } else {
                    for (int k = off; k < nf; ++k)
                        __builtin_nontemporal_store(s_m[p][k], &obase[k]);
                }
            }
        }
        // next iteration scatters into buf[p^1]; writeback of buf[p] already
        // consumed its LDS reads (data-dep before the stores), and the next
        // scatter into buf[p] only happens after the NEXT barrier. Safe with
        // one barrier per iteration.
    }
}

extern "C" void kernel_launch(void* const* d_in, const int* in_sizes, int n_in,
                              void* d_out, int out_size, void* d_ws, size_t ws_size,
                              hipStream_t stream) {
    const float* weights = (const float*)d_in[0];
    const float* bins    = (const float*)d_in[1];
    const float* max_bin = (const float*)d_in[2];
    float* out = (float*)d_out;
    const int n_rays = in_sizes[2];  // one max_bin entry per ray
    pdf_sampler_kernel<<<kGrid, kBlock, 0, stream>>>(weights, bins, max_bin, out, n_rays);
}